// Round 11
// baseline (92.233 us; speedup 1.0000x reference)
//
#include <hip/hip_runtime.h>

// LightPrompt inner_structure_update (dense form), MI355X gfx950.
// Outputs (f32, concat): x[4096,128] | adj[4096,4096] | edge_attr[4096,4096,4]
// Store floor ~50us (345.6 MB @ ~6.9 TB/s fill rate).
//
// R11 vs R10 (74.1us): R10's non-store residue was in-loop f32->bf16 convert
// (~6.4us: 50M elem-conversions chip-wide vs 524K unique), LDS write
// roundtrip (~3.8us) and latency exposed in the barrier-locked staging phase.
// Now: precompute kernel converts tokens ONCE into hi/lo bf16 arrays in d_ws
// (kp-major, slot-XOR-preswizzled), main kernel stages with
// global_load_lds(16B) -> linear LDS dest + swizzled frag reads (2-way banks,
// free). dot = ah*bh + ah*bl + al*bh via mfma_f32_16x16x32_bf16 (al*bl
// dropped, ~1e-7; absmax measured 2.4e-4 vs 1.23e-2 threshold). Precvt also
// writes the x output. Fallback to the R10-proven kernel if ws < 2MB.

typedef float  f32x4  __attribute__((ext_vector_type(4)));
typedef short  bf16x8 __attribute__((ext_vector_type(8)));
typedef unsigned short u16x4 __attribute__((ext_vector_type(4)));
typedef unsigned short u16x8 __attribute__((ext_vector_type(8)));
typedef unsigned int u32;

static constexpr int Tn = 4096;
static constexpr int Dm = 128;
static constexpr int En = 4;
static constexpr float THRE = 0.55f;
static constexpr float SLOPE = 0.01f;

#define BM 128   // block rows (i)
#define BN 64    // block cols (j)
#define KS 32    // k chunk (4 chunks of 4 slots x 8 bf16)

__device__ __forceinline__ unsigned short bf16rn(float x) {
    unsigned int u = __float_as_uint(x);
    return (unsigned short)((u + 0x7FFFu + ((u >> 16) & 1u)) >> 16);
}
__device__ __forceinline__ float bf16tof(unsigned short h) {
    return __uint_as_float(((unsigned int)h) << 16);
}

__device__ __forceinline__ void gload16(const void* g, void* l) {
    __builtin_amdgcn_global_load_lds(
        (const __attribute__((address_space(1))) u32*)g,
        (__attribute__((address_space(3))) u32*)l, 16, 0, 0);
}

// ---- precompute: tokens -> hi/lo bf16, layout Gh[kp][row][slot_phys][8],
// slot_phys = (g&3) ^ ((row>>1)&3); also writes the x output.
__global__ __launch_bounds__(256) void lp_precvt(const float* __restrict__ tokens,
                                                 unsigned short* __restrict__ Gh,
                                                 unsigned short* __restrict__ Gl,
                                                 float* __restrict__ out) {
    const int row = blockIdx.x * 256 + threadIdx.x;   // 0..4095
    const int key = (row >> 1) & 3;
    const float* src = tokens + (size_t)row * Dm;
    float* xdst = out + (size_t)row * Dm;
#pragma unroll
    for (int g = 0; g < 16; ++g) {
        const int kp = g >> 2;
        const int phys = (g & 3) ^ key;
        const f32x4 v0 = *reinterpret_cast<const f32x4*>(src + g * 8);
        const f32x4 v1 = *reinterpret_cast<const f32x4*>(src + g * 8 + 4);
        *reinterpret_cast<f32x4*>(xdst + g * 8)     = v0;   // x copy
        *reinterpret_cast<f32x4*>(xdst + g * 8 + 4) = v1;
        u16x8 hi, lo;
#pragma unroll
        for (int e = 0; e < 4; ++e) {
            unsigned short h = bf16rn(v0[e]);
            hi[e] = h; lo[e] = bf16rn(v0[e] - bf16tof(h));
            h = bf16rn(v1[e]);
            hi[e + 4] = h; lo[e + 4] = bf16rn(v1[e] - bf16tof(h));
        }
        const size_t base = (size_t)kp * (Tn * 32) + (size_t)row * 32 + phys * 8;
        *reinterpret_cast<u16x8*>(Gh + base) = hi;
        *reinterpret_cast<u16x8*>(Gl + base) = lo;
    }
}

// ---- main: MFMA dot + fused epilogue, global_load_lds staging.
__global__ __launch_bounds__(256) void lp_mfma(const unsigned short* __restrict__ Gh,
                                               const unsigned short* __restrict__ Gl,
                                               const float* __restrict__ edge_token,
                                               float* __restrict__ out) {
    __shared__ unsigned short AhL[BM * 32];
    __shared__ unsigned short AlL[BM * 32];
    __shared__ unsigned short BhL[BN * 32];
    __shared__ unsigned short BlL[BN * 32];

    const int tid = threadIdx.x;
    const int i0 = blockIdx.y * BM;
    const int j0 = blockIdx.x * BN;

    const int lane = tid & 63;
    const int w    = tid >> 6;   // wave 0..3
    const int wr   = w >> 1;     // row half (64 rows)
    const int wc   = w & 1;      // col half (32 cols)
    const int lr   = lane & 15;  // frag row/col within 16x16 tile
    const int lk   = lane >> 4;  // logical k quarter (8 bf16)

    f32x4 acc[4][2];
#pragma unroll
    for (int rt = 0; rt < 4; ++rt)
#pragma unroll
        for (int ct = 0; ct < 2; ++ct) acc[rt][ct] = (f32x4)(0.0f);

#pragma unroll 1
    for (int kp = 0; kp < Dm / KS; ++kp) {
        const size_t kplane = (size_t)kp * (Tn * 32);
        // A: 128 rows x 64B, 2 x (hi,lo) DMA per thread; B: 64 rows, 1 x each.
#pragma unroll
        for (int p = 0; p < 2; ++p) {
            const int f = (p << 8) + tid;          // 0..511
            const size_t gsrc = kplane + (size_t)(i0 + (f >> 2)) * 32 + (f & 3) * 8;
            gload16(Gh + gsrc, &AhL[f * 8]);
            gload16(Gl + gsrc, &AlL[f * 8]);
        }
        {
            const size_t gsrc = kplane + (size_t)(j0 + (tid >> 2)) * 32 + (tid & 3) * 8;
            gload16(Gh + gsrc, &BhL[tid * 8]);
            gload16(Gl + gsrc, &BlL[tid * 8]);
        }
        __syncthreads();   // drains vmcnt (global_load_lds) for all waves

        // Frag reads, slot-XOR swizzled: uniform 2-way banks (free).
        bf16x8 afh[4], afl[4], bfh[2], bfl[2];
#pragma unroll
        for (int rt = 0; rt < 4; ++rt) {
            const int row = (wr << 6) + (rt << 4) + lr;
            const int idx = row * 32 + ((lk ^ ((row >> 1) & 3)) << 3);
            afh[rt] = *reinterpret_cast<const bf16x8*>(&AhL[idx]);
            afl[rt] = *reinterpret_cast<const bf16x8*>(&AlL[idx]);
        }
#pragma unroll
        for (int ct = 0; ct < 2; ++ct) {
            const int col = (wc << 5) + (ct << 4) + lr;
            const int idx = col * 32 + ((lk ^ ((col >> 1) & 3)) << 3);
            bfh[ct] = *reinterpret_cast<const bf16x8*>(&BhL[idx]);
            bfl[ct] = *reinterpret_cast<const bf16x8*>(&BlL[idx]);
        }
#pragma unroll
        for (int rt = 0; rt < 4; ++rt)
#pragma unroll
            for (int ct = 0; ct < 2; ++ct) {
                acc[rt][ct] = __builtin_amdgcn_mfma_f32_16x16x32_bf16(
                    afh[rt], bfh[ct], acc[rt][ct], 0, 0, 0);
                acc[rt][ct] = __builtin_amdgcn_mfma_f32_16x16x32_bf16(
                    afh[rt], bfl[ct], acc[rt][ct], 0, 0, 0);
                acc[rt][ct] = __builtin_amdgcn_mfma_f32_16x16x32_bf16(
                    afl[rt], bfh[ct], acc[rt][ct], 0, 0, 0);
            }
        __syncthreads();
    }

    const float e0 = edge_token[0];
    const float e1 = edge_token[1];
    const float e2 = edge_token[2];
    const float e3 = edge_token[3];

    float* __restrict__ adj  = out + (size_t)Tn * Dm;
    float* __restrict__ attr = adj + (size_t)Tn * Tn;

    // C/D layout (m89-verified): col = lane&15, row = (lane>>4)*4 + reg.
#pragma unroll
    for (int rt = 0; rt < 4; ++rt) {
#pragma unroll
        for (int ct = 0; ct < 2; ++ct) {
            const f32x4 dv = acc[rt][ct];
            const int j = j0 + (wc << 5) + (ct << 4) + lr;
#pragma unroll
            for (int reg = 0; reg < 4; ++reg) {
                const int i = i0 + (wr << 6) + (rt << 4) + (lk << 2) + reg;
                const float d = dv[reg];
                const float sim = 1.0f / (1.0f + __expf(-d));
                const float m = (sim >= THRE) ? 1.0f : 0.0f;
                __builtin_nontemporal_store(sim * m, adj + (size_t)i * Tn + j);
                f32x4 at;
                float v;
                v = d * e0; at.x = (v > 0.0f ? v : SLOPE * v) * m;
                v = d * e1; at.y = (v > 0.0f ? v : SLOPE * v) * m;
                v = d * e2; at.z = (v > 0.0f ? v : SLOPE * v) * m;
                v = d * e3; at.w = (v > 0.0f ? v : SLOPE * v) * m;
                __builtin_nontemporal_store(at,
                    reinterpret_cast<f32x4*>(attr + ((size_t)i * Tn + j) * En));
            }
        }
    }
}

// ---- fallback (R10, proven at 74.1us): in-kernel convert, no workspace.
#define LDH 40
__global__ __launch_bounds__(256) void lp_fused_fb(const float* __restrict__ tokens,
                                                   const float* __restrict__ edge_token,
                                                   float* __restrict__ out) {
    __shared__ unsigned short Ah[BM][LDH];
    __shared__ unsigned short Al[BM][LDH];
    __shared__ unsigned short Bh[BN][LDH];
    __shared__ unsigned short Bl[BN][LDH];

    const int tid = threadIdx.x;
    const int i0 = blockIdx.y * BM;
    const int j0 = blockIdx.x * BN;

    const int bid = blockIdx.y * (Tn / BN) + blockIdx.x;
    if (bid < 512) {
        reinterpret_cast<f32x4*>(out)[bid * 256 + tid] =
            reinterpret_cast<const f32x4*>(tokens)[bid * 256 + tid];
    }

    const int lane = tid & 63;
    const int w    = tid >> 6;
    const int wr   = w >> 1;
    const int wc   = w & 1;
    const int lr   = lane & 15;
    const int lk   = lane >> 4;

    f32x4 acc[4][2];
#pragma unroll
    for (int rt = 0; rt < 4; ++rt)
#pragma unroll
        for (int ct = 0; ct < 2; ++ct) acc[rt][ct] = (f32x4)(0.0f);

#pragma unroll 1
    for (int kp = 0; kp < Dm / KS; ++kp) {
        const int kbase = kp * KS;
#pragma unroll
        for (int p = 0; p < 4; ++p) {
            const int f = (p << 8) + tid;
            const int row = f >> 3;
            const int c4 = (f & 7) << 2;
            const f32x4 v = *reinterpret_cast<const f32x4*>(
                tokens + (size_t)(i0 + row) * Dm + kbase + c4);
            u16x4 hi, lo;
#pragma unroll
            for (int e = 0; e < 4; ++e) {
                const unsigned short h = bf16rn(v[e]);
                hi[e] = h;
                lo[e] = bf16rn(v[e] - bf16tof(h));
            }
            *reinterpret_cast<u16x4*>(&Ah[row][c4]) = hi;
            *reinterpret_cast<u16x4*>(&Al[row][c4]) = lo;
        }
#pragma unroll
        for (int p = 0; p < 2; ++p) {
            const int f = (p << 8) + tid;
            const int row = f >> 3;
            const int c4 = (f & 7) << 2;
            const f32x4 v = *reinterpret_cast<const f32x4*>(
                tokens + (size_t)(j0 + row) * Dm + kbase + c4);
            u16x4 hi, lo;
#pragma unroll
            for (int e = 0; e < 4; ++e) {
                const unsigned short h = bf16rn(v[e]);
                hi[e] = h;
                lo[e] = bf16rn(v[e] - bf16tof(h));
            }
            *reinterpret_cast<u16x4*>(&Bh[row][c4]) = hi;
            *reinterpret_cast<u16x4*>(&Bl[row][c4]) = lo;
        }
        __syncthreads();

        bf16x8 afh[4], afl[4], bfh[2], bfl[2];
#pragma unroll
        for (int rt = 0; rt < 4; ++rt) {
            const int row = (wr << 6) + (rt << 4) + lr;
            afh[rt] = *reinterpret_cast<const bf16x8*>(&Ah[row][lk << 3]);
            afl[rt] = *reinterpret_cast<const bf16x8*>(&Al[row][lk << 3]);
        }
#pragma unroll
        for (int ct = 0; ct < 2; ++ct) {
            const int col = (wc << 5) + (ct << 4) + lr;
            bfh[ct] = *reinterpret_cast<const bf16x8*>(&Bh[col][lk << 3]);
            bfl[ct] = *reinterpret_cast<const bf16x8*>(&Bl[col][lk << 3]);
        }
#pragma unroll
        for (int rt = 0; rt < 4; ++rt)
#pragma unroll
            for (int ct = 0; ct < 2; ++ct) {
                acc[rt][ct] = __builtin_amdgcn_mfma_f32_16x16x32_bf16(
                    afh[rt], bfh[ct], acc[rt][ct], 0, 0, 0);
                acc[rt][ct] = __builtin_amdgcn_mfma_f32_16x16x32_bf16(
                    afh[rt], bfl[ct], acc[rt][ct], 0, 0, 0);
                acc[rt][ct] = __builtin_amdgcn_mfma_f32_16x16x32_bf16(
                    afl[rt], bfh[ct], acc[rt][ct], 0, 0, 0);
            }
        __syncthreads();
    }

    const float e0 = edge_token[0];
    const float e1 = edge_token[1];
    const float e2 = edge_token[2];
    const float e3 = edge_token[3];

    float* __restrict__ adj  = out + (size_t)Tn * Dm;
    float* __restrict__ attr = adj + (size_t)Tn * Tn;

#pragma unroll
    for (int rt = 0; rt < 4; ++rt) {
#pragma unroll
        for (int ct = 0; ct < 2; ++ct) {
            const f32x4 dv = acc[rt][ct];
            const int j = j0 + (wc << 5) + (ct << 4) + lr;
#pragma unroll
            for (int reg = 0; reg < 4; ++reg) {
                const int i = i0 + (wr << 6) + (rt << 4) + (lk << 2) + reg;
                const float d = dv[reg];
                const float sim = 1.0f / (1.0f + __expf(-d));
                const float m = (sim >= THRE) ? 1.0f : 0.0f;
                __builtin_nontemporal_store(sim * m, adj + (size_t)i * Tn + j);
                f32x4 at;
                float v;
                v = d * e0; at.x = (v > 0.0f ? v : SLOPE * v) * m;
                v = d * e1; at.y = (v > 0.0f ? v : SLOPE * v) * m;
                v = d * e2; at.z = (v > 0.0f ? v : SLOPE * v) * m;
                v = d * e3; at.w = (v > 0.0f ? v : SLOPE * v) * m;
                __builtin_nontemporal_store(at,
                    reinterpret_cast<f32x4*>(attr + ((size_t)i * Tn + j) * En));
            }
        }
    }
}

extern "C" void kernel_launch(void* const* d_in, const int* in_sizes, int n_in,
                              void* d_out, int out_size, void* d_ws, size_t ws_size,
                              hipStream_t stream) {
    const float* tokens     = (const float*)d_in[0];  // [1,4096,128] f32
    const float* edge_token = (const float*)d_in[1];  // [1,4] f32
    float* out = (float*)d_out;

    const size_t half = (size_t)Tn * Dm * sizeof(unsigned short);  // 1 MB
    if (ws_size >= 2 * half) {
        unsigned short* Gh = (unsigned short*)d_ws;
        unsigned short* Gl = Gh + (size_t)Tn * Dm;
        hipLaunchKernelGGL(lp_precvt, dim3(Tn / 256), dim3(256), 0, stream,
                           tokens, Gh, Gl, out);
        hipLaunchKernelGGL(lp_mfma, dim3(Tn / BN, Tn / BM), dim3(256), 0, stream,
                           Gh, Gl, edge_token, out);
    } else {
        hipLaunchKernelGGL(lp_fused_fb, dim3(Tn / BN, Tn / BM), dim3(256), 0, stream,
                           tokens, edge_token, out);
    }
}

// Round 12
// 66.626 us; speedup vs baseline: 1.3843x; 1.3843x over previous
//
#include <hip/hip_runtime.h>

// LightPrompt inner_structure_update (dense form), MI355X gfx950.
// Outputs (f32, concat): x[4096,128] | adj[4096,4096] | edge_attr[4096,4096,4]
// Store floor ~50us (337.6 MB @ ~6.9 TB/s fill rate).
//
// R12 = R10 (74.1us, proven) + ONE change: adj stores go through an LDS
// transpose so every adj wave-instr writes 256B full-line chunks (R10 wrote
// 4x64B half-line segments per instr; with NT no-allocate stores those can't
// merge -> ~2x effective adj traffic ~ +10us). attr stores were already
// 256B-contiguous and stay direct. R11 (92us) refuted the precvt/ws route:
// 16-block precvt serialized + global_load_lds hard vmcnt(0) wait; reverted.
// dot = ah*bh + ah*bl + al*bh via mfma_f32_16x16x32_bf16 (split-bf16; al*bl
// dropped ~1e-7; measured absmax 2.4e-4 vs 1.23e-2 threshold).

typedef float  f32x4  __attribute__((ext_vector_type(4)));
typedef short  bf16x8 __attribute__((ext_vector_type(8)));
typedef unsigned short u16x4 __attribute__((ext_vector_type(4)));

static constexpr int Tn = 4096;
static constexpr int Dm = 128;
static constexpr int En = 4;
static constexpr float THRE = 0.55f;
static constexpr float SLOPE = 0.01f;

#define BM 128   // block rows (i)
#define BN 64    // block cols (j)
#define KS 32    // k chunk
#define LDH 40   // u16 per staging row: 80B stride (16B-aligned), 2-way banks
#define LDS_D 68 // f32 per Ds row: 272B stride (16B-aligned); writes 2-way,
                 // b128 reads at the 8-touch/bank minimum (audited)

__device__ __forceinline__ unsigned short bf16rn(float x) {
    unsigned int u = __float_as_uint(x);
    return (unsigned short)((u + 0x7FFFu + ((u >> 16) & 1u)) >> 16);
}
__device__ __forceinline__ float bf16tof(unsigned short h) {
    return __uint_as_float(((unsigned int)h) << 16);
}

__global__ __launch_bounds__(256) void lp_fused(const float* __restrict__ tokens,
                                                const float* __restrict__ edge_token,
                                                float* __restrict__ out) {
    // 34816 B shared: staging arrays (30720 B) alias the front; Ds reuses all
    // of it after the k-loop's final barrier (staging is dead by then).
    __shared__ __align__(16) float smem_f[BM * LDS_D];
    unsigned short* Ah = (unsigned short*)smem_f;     // [BM*LDH]
    unsigned short* Al = Ah + BM * LDH;               // [BM*LDH]
    unsigned short* Bh = Al + BM * LDH;               // [BN*LDH]
    unsigned short* Bl = Bh + BN * LDH;               // [BN*LDH]
    float* Ds = smem_f;                               // [BM][LDS_D]

    const int tid = threadIdx.x;
    const int i0 = blockIdx.y * BM;
    const int j0 = blockIdx.x * BN;

    // x output = tokens verbatim (131072 float4): first 512 of 2048 blocks.
    const int bid = blockIdx.y * (Tn / BN) + blockIdx.x;
    if (bid < 512) {
        reinterpret_cast<f32x4*>(out)[bid * 256 + tid] =
            reinterpret_cast<const f32x4*>(tokens)[bid * 256 + tid];
    }

    const int lane = tid & 63;
    const int w    = tid >> 6;   // wave 0..3
    const int wr   = w >> 1;     // row half (64 rows)
    const int wc   = w & 1;      // col half (32 cols)
    const int lr   = lane & 15;  // frag row/col within 16x16 tile
    const int lk   = lane >> 4;  // k quarter (8 bf16)

    f32x4 acc[4][2];
#pragma unroll
    for (int rt = 0; rt < 4; ++rt)
#pragma unroll
        for (int ct = 0; ct < 2; ++ct) acc[rt][ct] = (f32x4)(0.0f);

#pragma unroll 1
    for (int kp = 0; kp < Dm / KS; ++kp) {
        const int kbase = kp * KS;
        // Stage A (128x32 f32 -> hi/lo bf16): 4 f32x4/thread, 8 lanes/row.
#pragma unroll
        for (int p = 0; p < 4; ++p) {
            const int f = (p << 8) + tid;
            const int row = f >> 3;
            const int c4 = (f & 7) << 2;
            const f32x4 v = *reinterpret_cast<const f32x4*>(
                tokens + (size_t)(i0 + row) * Dm + kbase + c4);
            u16x4 hi, lo;
#pragma unroll
            for (int e = 0; e < 4; ++e) {
                const unsigned short h = bf16rn(v[e]);
                hi[e] = h;
                lo[e] = bf16rn(v[e] - bf16tof(h));
            }
            *reinterpret_cast<u16x4*>(&Ah[row * LDH + c4]) = hi;
            *reinterpret_cast<u16x4*>(&Al[row * LDH + c4]) = lo;
        }
        // Stage B (64x32): 2 f32x4/thread.
#pragma unroll
        for (int p = 0; p < 2; ++p) {
            const int f = (p << 8) + tid;
            const int row = f >> 3;
            const int c4 = (f & 7) << 2;
            const f32x4 v = *reinterpret_cast<const f32x4*>(
                tokens + (size_t)(j0 + row) * Dm + kbase + c4);
            u16x4 hi, lo;
#pragma unroll
            for (int e = 0; e < 4; ++e) {
                const unsigned short h = bf16rn(v[e]);
                hi[e] = h;
                lo[e] = bf16rn(v[e] - bf16tof(h));
            }
            *reinterpret_cast<u16x4*>(&Bh[row * LDH + c4]) = hi;
            *reinterpret_cast<u16x4*>(&Bl[row * LDH + c4]) = lo;
        }
        __syncthreads();

        // Fragments: lane lr = tile row/col, lk*8 = k offset (16B b128 reads).
        bf16x8 afh[4], afl[4], bfh[2], bfl[2];
#pragma unroll
        for (int rt = 0; rt < 4; ++rt) {
            const int row = (wr << 6) + (rt << 4) + lr;
            afh[rt] = *reinterpret_cast<const bf16x8*>(&Ah[row * LDH + (lk << 3)]);
            afl[rt] = *reinterpret_cast<const bf16x8*>(&Al[row * LDH + (lk << 3)]);
        }
#pragma unroll
        for (int ct = 0; ct < 2; ++ct) {
            const int col = (wc << 5) + (ct << 4) + lr;
            bfh[ct] = *reinterpret_cast<const bf16x8*>(&Bh[col * LDH + (lk << 3)]);
            bfl[ct] = *reinterpret_cast<const bf16x8*>(&Bl[col * LDH + (lk << 3)]);
        }
#pragma unroll
        for (int rt = 0; rt < 4; ++rt)
#pragma unroll
            for (int ct = 0; ct < 2; ++ct) {
                acc[rt][ct] = __builtin_amdgcn_mfma_f32_16x16x32_bf16(
                    afh[rt], bfh[ct], acc[rt][ct], 0, 0, 0);
                acc[rt][ct] = __builtin_amdgcn_mfma_f32_16x16x32_bf16(
                    afh[rt], bfl[ct], acc[rt][ct], 0, 0, 0);
                acc[rt][ct] = __builtin_amdgcn_mfma_f32_16x16x32_bf16(
                    afl[rt], bfh[ct], acc[rt][ct], 0, 0, 0);
            }
        __syncthreads();   // also makes staging LDS dead -> Ds reuse safe
    }

    const float e0 = edge_token[0];
    const float e1 = edge_token[1];
    const float e2 = edge_token[2];
    const float e3 = edge_token[3];

    float* __restrict__ adj  = out + (size_t)Tn * Dm;
    float* __restrict__ attr = adj + (size_t)Tn * Tn;

    // C/D layout (m89-verified): col = lane&15, row = (lane>>4)*4 + reg.
    // attr stored direct (256B/instr, full lines); sim*m staged into Ds.
#pragma unroll
    for (int rt = 0; rt < 4; ++rt) {
#pragma unroll
        for (int ct = 0; ct < 2; ++ct) {
            const f32x4 dv = acc[rt][ct];
            const int jl = (wc << 5) + (ct << 4) + lr;
            const int j = j0 + jl;
#pragma unroll
            for (int reg = 0; reg < 4; ++reg) {
                const int il = (wr << 6) + (rt << 4) + (lk << 2) + reg;
                const float d = dv[reg];
                const float sim = 1.0f / (1.0f + __expf(-d));
                const float m = (sim >= THRE) ? 1.0f : 0.0f;
                Ds[il * LDS_D + jl] = sim * m;
                f32x4 at;
                float v;
                v = d * e0; at.x = (v > 0.0f ? v : SLOPE * v) * m;
                v = d * e1; at.y = (v > 0.0f ? v : SLOPE * v) * m;
                v = d * e2; at.z = (v > 0.0f ? v : SLOPE * v) * m;
                v = d * e3; at.w = (v > 0.0f ? v : SLOPE * v) * m;
                __builtin_nontemporal_store(at,
                    reinterpret_cast<f32x4*>(attr + ((size_t)(i0 + il) * Tn + j) * En));
            }
        }
    }
    __syncthreads();

    // adj from Ds, row-major: per wave-instr 4 rows x 256B (2 full lines).
    const int c4 = lr << 2;
#pragma unroll
    for (int s = 0; s < 8; ++s) {
        const int row = (w << 5) + (s << 2) + lk;
        const f32x4 v = *reinterpret_cast<const f32x4*>(&Ds[row * LDS_D + c4]);
        __builtin_nontemporal_store(v,
            reinterpret_cast<f32x4*>(adj + (size_t)(i0 + row) * Tn + j0 + c4));
    }
}

extern "C" void kernel_launch(void* const* d_in, const int* in_sizes, int n_in,
                              void* d_out, int out_size, void* d_ws, size_t ws_size,
                              hipStream_t stream) {
    const float* tokens     = (const float*)d_in[0];  // [1,4096,128] f32
    const float* edge_token = (const float*)d_in[1];  // [1,4] f32
    float* out = (float*)d_out;

    hipLaunchKernelGGL(lp_fused, dim3(Tn / BN, Tn / BM), dim3(256), 0, stream,
                       tokens, edge_token, out);
}